// Round 1
// baseline (123.085 us; speedup 1.0000x reference)
//
#include <hip/hip_runtime.h>

#define EPSILON 1e-6f
#define NADMIN 256
#define NBATCH 16
#define NPIX (1024 * 1024)   // H*W per batch

// ---------------------------------------------------------------------------
// Pass 1: per-batch segment sum into S[b][a], via per-block LDS histogram.
// grid = (blocks_per_batch, NBATCH), block = 256
// ---------------------------------------------------------------------------
__global__ __launch_bounds__(256) void segsum_kernel(
    const float* __restrict__ P,
    const int* __restrict__ ids,
    float* __restrict__ S)
{
    __shared__ float s_bins[NADMIN];
    const int b = blockIdx.y;
    for (int i = threadIdx.x; i < NADMIN; i += blockDim.x) s_bins[i] = 0.0f;
    __syncthreads();

    const float4* __restrict__ p4  = (const float4*)(P   + (size_t)b * NPIX);
    const int4*   __restrict__ id4 = (const int4*)  (ids + (size_t)b * NPIX);
    const int nvec = NPIX / 4;
    const int stride = gridDim.x * blockDim.x;

    for (int i = blockIdx.x * blockDim.x + threadIdx.x; i < nvec; i += stride) {
        float4 p = p4[i];
        int4   d = id4[i];
        if (d.x >= 0) atomicAdd(&s_bins[d.x], p.x);
        if (d.y >= 0) atomicAdd(&s_bins[d.y], p.y);
        if (d.z >= 0) atomicAdd(&s_bins[d.z], p.z);
        if (d.w >= 0) atomicAdd(&s_bins[d.w], p.w);
    }
    __syncthreads();

    for (int i = threadIdx.x; i < NADMIN; i += blockDim.x) {
        float v = s_bins[i];
        if (v != 0.0f) atomicAdd(&S[b * NADMIN + i], v);
    }
}

// ---------------------------------------------------------------------------
// Tiny pass: R[b][a] = census[b][a] / (S[b][a] + eps)
// ---------------------------------------------------------------------------
__global__ void ratio_kernel(const float* __restrict__ S,
                             const float* __restrict__ census,
                             float* __restrict__ R)
{
    int i = blockIdx.x * blockDim.x + threadIdx.x;
    if (i < NBATCH * NADMIN) R[i] = census[i] / (S[i] + EPSILON);
}

// ---------------------------------------------------------------------------
// Pass 2: out = valid ? p * R[b][id] : p   (R staged in LDS, 1 KB)
// grid = (blocks_per_batch, NBATCH), block = 256
// ---------------------------------------------------------------------------
__global__ __launch_bounds__(256) void apply_kernel(
    const float* __restrict__ P,
    const int* __restrict__ ids,
    const float* __restrict__ R,
    float* __restrict__ out)
{
    __shared__ float s_R[NADMIN];
    const int b = blockIdx.y;
    for (int i = threadIdx.x; i < NADMIN; i += blockDim.x) s_R[i] = R[b * NADMIN + i];
    __syncthreads();

    const float4* __restrict__ p4  = (const float4*)(P   + (size_t)b * NPIX);
    const int4*   __restrict__ id4 = (const int4*)  (ids + (size_t)b * NPIX);
    float4* __restrict__ o4 = (float4*)(out + (size_t)b * NPIX);
    const int nvec = NPIX / 4;
    const int stride = gridDim.x * blockDim.x;

    for (int i = blockIdx.x * blockDim.x + threadIdx.x; i < nvec; i += stride) {
        float4 p = p4[i];
        int4   d = id4[i];
        float4 o;
        o.x = (d.x >= 0) ? p.x * s_R[d.x] : p.x;
        o.y = (d.y >= 0) ? p.y * s_R[d.y] : p.y;
        o.z = (d.z >= 0) ? p.z * s_R[d.z] : p.z;
        o.w = (d.w >= 0) ? p.w * s_R[d.w] : p.w;
        o4[i] = o;
    }
}

extern "C" void kernel_launch(void* const* d_in, const int* in_sizes, int n_in,
                              void* d_out, int out_size, void* d_ws, size_t ws_size,
                              hipStream_t stream)
{
    const float* P      = (const float*)d_in[0];   // (B,1,H,W) f32
    const int*   ids    = (const int*)d_in[1];     // (B,H,W) i32
    const float* census = (const float*)d_in[2];   // (B,A) f32
    float* out = (float*)d_out;

    float* S = (float*)d_ws;                       // (B,A) segment sums
    float* R = S + NBATCH * NADMIN;                // (B,A) ratios

    // Zero S each call (ws is poisoned once, never restored between replays).
    hipMemsetAsync(S, 0, NBATCH * NADMIN * sizeof(float), stream);

    dim3 block(256);
    dim3 grid(128, NBATCH);   // 2048 blocks total, grid-stride over 256K float4/batch

    segsum_kernel<<<grid, block, 0, stream>>>(P, ids, S);
    ratio_kernel<<<(NBATCH * NADMIN + 255) / 256, 256, 0, stream>>>(S, census, R);
    apply_kernel<<<grid, block, 0, stream>>>(P, ids, R, out);
}